// Round 8
// baseline (379.401 us; speedup 1.0000x reference)
//
#include <hip/hip_runtime.h>
#include <math.h>

// LSTM autoencoder, single timestep, h0=c0=0.
// => whh unused; f-gate unused. Fused single kernel, 7 phases.
// DATAFLOW pipeline: no global barriers. Each h vector is split into
// 256-element chunks; row-writers bump a per-chunk counter (release, agent
// scope); consumer waves poll only the chunks covering their column slice
// (relaxed, s_sleep backoff). h values move via agent-scope relaxed atomics
// (coherence point; no cache maintenance). Weights are read-only => normal
// cached loads. 256 blocks x 1024 threads = 4096 waves, 1 block/CU.

#define NB 256
#define NT 1024
#define NWAVE (NT / 64)                 // 16 waves/block
#define PAD 32                          // u32 per counter line (128 B)
#define CNT_LINES 16                    // counter lines per phase boundary
#define CNT_REGION_U32 4096             // 16 KB zeroed per call

typedef float v4f __attribute__((ext_vector_type(4)));

__device__ __forceinline__ float sigmoidf_(float v) {
    return 1.0f / (1.0f + expf(-v));
}

__device__ __forceinline__ float wred(float v) {
    #pragma unroll
    for (int off = 32; off > 0; off >>= 1) v += __shfl_xor(v, off, 64);
    return v;
}

__device__ __forceinline__ void st_agent(float* p, float v) {
    __hip_atomic_store(p, v, __ATOMIC_RELAXED, __HIP_MEMORY_SCOPE_AGENT);
}

__device__ __forceinline__ unsigned long long aload64(const float* p) {
    return __hip_atomic_load((const unsigned long long*)p,
                             __ATOMIC_RELAXED, __HIP_MEMORY_SCOPE_AGENT);
}

// Wait until chunks [c0, c0+nch) of the producer phase are complete
// (counter == 256 rows per chunk). Lane-parallel poll, one line per lane.
__device__ __forceinline__ void wait_chunks(const unsigned* cnt_base,
                                            int c0, int nch, int lane) {
    const bool mine = lane < nch;
    const unsigned* myp = cnt_base + (size_t)(c0 + (mine ? lane : 0)) * PAD;
    while (true) {
        unsigned v = mine ? __hip_atomic_load(myp, __ATOMIC_RELAXED,
                                              __HIP_MEMORY_SCOPE_AGENT)
                          : 256u;
        if (__all(v >= 256u)) break;
        __builtin_amdgcn_s_sleep(4);
    }
}

// One phase. Cin = input dim, SPLIT waves/row (column split), tasks = wv.
// LSTM=true: rows j (i), j+2dh (g), j+3dh (o); else plain linear row j.
// ATOMX: read x slice via agent atomics (cross-block data). WAIT: poll deps.
template<int Cin, int SPLIT, bool ATOMX, bool WAIT, bool LSTM>
__device__ __forceinline__ void phase(const float* __restrict__ w,
                                      const float* __restrict__ bi,
                                      const float* __restrict__ bh,
                                      const float* __restrict__ xsrc,
                                      float* __restrict__ hdst,
                                      const unsigned* cnt_in,
                                      unsigned* cnt_out,
                                      int dh, int wv, int wl, int lane,
                                      float (*red)[3]) {
    constexpr int CL = Cin / SPLIT;     // cols per task
    constexpr int NG = CL / 256;        // 256-col groups per task
    const int j = wv / SPLIT;
    const int part = wv % SPLIT;
    const int off = part * CL;

    if constexpr (WAIT) wait_chunks(cnt_in, off >> 8, NG, lane);
    __builtin_amdgcn_sched_barrier(0);

    // x slice -> registers (static indices only).
    float xr[NG * 4];
    #pragma unroll
    for (int g = 0; g < NG; ++g) {
        const int c = off + g * 256 + lane * 4;
        if constexpr (ATOMX) {
            union { unsigned long long u; float f[2]; } a, b;
            a.u = aload64(xsrc + c);
            b.u = aload64(xsrc + c + 2);
            xr[g * 4 + 0] = a.f[0]; xr[g * 4 + 1] = a.f[1];
            xr[g * 4 + 2] = b.f[0]; xr[g * 4 + 3] = b.f[1];
        } else {
            const v4f v = *reinterpret_cast<const v4f*>(xsrc + c);
            xr[g * 4 + 0] = v.x; xr[g * 4 + 1] = v.y;
            xr[g * 4 + 2] = v.z; xr[g * 4 + 3] = v.w;
        }
    }

    const float* wi = w + (size_t)j * Cin + off;
    const float* wg = w + ((size_t)j + 2u * (size_t)dh) * Cin + off;
    const float* wo = w + ((size_t)j + 3u * (size_t)dh) * Cin + off;

    float si = 0.f, sg = 0.f, so = 0.f;
    #pragma unroll
    for (int g = 0; g < NG; ++g) {
        const int c = g * 256 + lane * 4;
        const v4f av = *reinterpret_cast<const v4f*>(wi + c);
        si += av.x * xr[g*4] + av.y * xr[g*4+1] + av.z * xr[g*4+2] + av.w * xr[g*4+3];
        if constexpr (LSTM) {
            const v4f gv = *reinterpret_cast<const v4f*>(wg + c);
            const v4f ov = *reinterpret_cast<const v4f*>(wo + c);
            sg += gv.x * xr[g*4] + gv.y * xr[g*4+1] + gv.z * xr[g*4+2] + gv.w * xr[g*4+3];
            so += ov.x * xr[g*4] + ov.y * xr[g*4+1] + ov.z * xr[g*4+2] + ov.w * xr[g*4+3];
        }
    }
    si = wred(si);
    if constexpr (LSTM) { sg = wred(sg); so = wred(so); }

    bool writer = (lane == 0);
    if constexpr (SPLIT > 1) {
        __syncthreads();                       // red[] reuse guard
        if (lane == 0) { red[wl][0] = si; red[wl][1] = sg; red[wl][2] = so; }
        __syncthreads();
        writer = (part == 0 && lane == 0);
        if (writer) {
            #pragma unroll
            for (int k = 1; k < SPLIT; ++k) {
                si += red[wl + k][0]; sg += red[wl + k][1]; so += red[wl + k][2];
            }
        }
    }
    if (writer) {
        if constexpr (LSTM) {
            const float gi = si + bi[j]          + bh[j];
            const float gg = sg + bi[j + 2 * dh] + bh[j + 2 * dh];
            const float go = so + bi[j + 3 * dh] + bh[j + 3 * dh];
            const float hv = sigmoidf_(go) * tanhf(sigmoidf_(gi) * tanhf(gg));
            st_agent(hdst + j, hv);
            __hip_atomic_fetch_add(cnt_out + (size_t)(j >> 8) * PAD, 1u,
                                   __ATOMIC_RELEASE, __HIP_MEMORY_SCOPE_AGENT);
        } else {
            hdst[j] = si + bi[j];
        }
    }
}

struct Params {
    const float *x;
    const float *w0, *bi0, *bh0;  // e1l0: 2048 rows, C=4096
    const float *w1, *bi1, *bh1;  // e1l1: 2048, C=2048
    const float *w2, *bi2, *bh2;  // e2:   1024, C=2048
    const float *w3, *bi3, *bh3;  // d1l0: 1024, C=1024
    const float *w4, *bi4, *bh4;  // d1l1: 1024, C=1024
    const float *w5, *bi5, *bh5;  // d2:   2048, C=1024
    const float *ow, *ob;         // out:  4096, C=2048
    float *out;
    float *ws;
};

__global__ __launch_bounds__(NT, 1) void fused_lstm_ae(Params p) {
    __shared__ float red[NWAVE][3];
    const int lane = threadIdx.x & 63;
    const int wl = threadIdx.x >> 6;
    const int wv = (int)blockIdx.x * NWAVE + wl;   // 0..4095

    unsigned* cnt = (unsigned*)p.ws;               // 16 KB, zeroed per call
    unsigned* c01 = cnt + 0 * CNT_LINES * PAD;     // h1 chunks (8)
    unsigned* c12 = cnt + 1 * CNT_LINES * PAD;     // h2 chunks (8)
    unsigned* c23 = cnt + 2 * CNT_LINES * PAD;     // z  chunks (4)
    unsigned* c34 = cnt + 3 * CNT_LINES * PAD;     // h3 chunks (4)
    unsigned* c45 = cnt + 4 * CNT_LINES * PAD;     // h4 chunks (4)
    unsigned* c56 = cnt + 5 * CNT_LINES * PAD;     // h5 chunks (8)

    float* hb = p.ws + CNT_REGION_U32;
    float* h1 = hb;            // 2048
    float* h2 = h1 + 2048;     // 2048
    float* z  = h2 + 2048;     // 1024
    float* h3 = z  + 1024;     // 1024
    float* h4 = h3 + 1024;     // 1024
    float* h5 = h4 + 1024;     // 2048

    phase<4096, 2, false, false, true>(p.w0, p.bi0, p.bh0, p.x, h1, nullptr, c01, 2048, wv, wl, lane, red);
    phase<2048, 2, true,  true,  true>(p.w1, p.bi1, p.bh1, h1,  h2, c01, c12, 2048, wv, wl, lane, red);
    phase<2048, 4, true,  true,  true>(p.w2, p.bi2, p.bh2, h2,  z,  c12, c23, 1024, wv, wl, lane, red);
    phase<1024, 4, true,  true,  true>(p.w3, p.bi3, p.bh3, z,   h3, c23, c34, 1024, wv, wl, lane, red);
    phase<1024, 4, true,  true,  true>(p.w4, p.bi4, p.bh4, h3,  h4, c34, c45, 1024, wv, wl, lane, red);
    phase<1024, 2, true,  true,  true>(p.w5, p.bi5, p.bh5, h4,  h5, c45, c56, 2048, wv, wl, lane, red);
    phase<2048, 1, true,  true,  false>(p.ow, p.ob, p.ob,  h5, p.out, c56, nullptr, 0, wv, wl, lane, red);
}

extern "C" void kernel_launch(void* const* d_in, const int* in_sizes, int n_in,
                              void* d_out, int out_size, void* d_ws, size_t ws_size,
                              hipStream_t stream)
{
    Params p;
    p.x   = (const float*)d_in[0];
    p.w0  = (const float*)d_in[1];
    p.bi0 = (const float*)d_in[3];
    p.bh0 = (const float*)d_in[4];
    p.w1  = (const float*)d_in[5];
    p.bi1 = (const float*)d_in[7];
    p.bh1 = (const float*)d_in[8];
    p.w2  = (const float*)d_in[9];
    p.bi2 = (const float*)d_in[11];
    p.bh2 = (const float*)d_in[12];
    p.w3  = (const float*)d_in[13];
    p.bi3 = (const float*)d_in[15];
    p.bh3 = (const float*)d_in[16];
    p.w4  = (const float*)d_in[17];
    p.bi4 = (const float*)d_in[19];
    p.bh4 = (const float*)d_in[20];
    p.w5  = (const float*)d_in[21];
    p.bi5 = (const float*)d_in[23];
    p.bh5 = (const float*)d_in[24];
    p.ow  = (const float*)d_in[25];
    p.ob  = (const float*)d_in[26];
    p.out = (float*)d_out;
    p.ws  = (float*)d_ws;

    // Zero the dataflow counters (must not persist across graph replays).
    hipMemsetAsync(d_ws, 0, CNT_REGION_U32 * sizeof(unsigned), stream);

    fused_lstm_ae<<<NB, NT, 0, stream>>>(p);
}

// Round 9
// 107.887 us; speedup vs baseline: 3.5167x; 3.5167x over previous
//
#include <hip/hip_runtime.h>
#include <math.h>

// LSTM autoencoder, single timestep, h0=c0=0.
// => whh unused; f-gate unused. Fused single kernel, 7 phases.
// Fence-free hierarchical grid barrier (R7-proven) at R4-proven parallelism:
// 512 blocks x 512 threads = 4096 waves, 16 waves/CU (2 blocks/CU; capacity
// 4 blocks/CU so plain-launch co-residency is guaranteed with 2x margin).
// h crosses blocks via agent-scope relaxed atomics (coherence point, no L2
// maintenance). Weights are read-only => normal cached loads.

#define NB 512
#define NT 512
#define NWAVE (NT / 64)                    // 8 waves/block
#define GRPSZ 8
#define NGRP (NB / GRPSZ)                  // 64 groups
#define PAD 32                             // u32 per line (128 B)
#define PHASE_U32 ((2 * NGRP + 1) * PAD)   // 4128
#define BAR_U32 32768                      // 128 KB barrier region

typedef float v4f __attribute__((ext_vector_type(4)));

__device__ __forceinline__ float sigmoidf_(float v) {
    return 1.0f / (1.0f + expf(-v));
}

__device__ __forceinline__ float wred(float v) {
    #pragma unroll
    for (int off = 32; off > 0; off >>= 1) v += __shfl_xor(v, off, 64);
    return v;
}

__device__ __forceinline__ void st_agent(float* p, float v) {
    __hip_atomic_store(p, v, __ATOMIC_RELAXED, __HIP_MEMORY_SCOPE_AGENT);
}

__device__ __forceinline__ unsigned long long aload64(const float* p) {
    return __hip_atomic_load((const unsigned long long*)p,
                             __ATOMIC_RELAXED, __HIP_MEMORY_SCOPE_AGENT);
}

// Fence-free hierarchical grid barrier (fresh counters per barrier).
__device__ __forceinline__ void gbar(unsigned* base) {
    __syncthreads();                      // drains vmcnt: h-stores complete
    if (threadIdx.x == 0) {
        const unsigned bid = blockIdx.x;
        const unsigned gid = bid >> 3;
        unsigned* garr = base + (size_t)gid * PAD;
        unsigned* ggo  = base + (size_t)(NGRP + gid) * PAD;
        unsigned* cent = base + (size_t)(2 * NGRP) * PAD;
        __hip_atomic_fetch_add(garr, 1u, __ATOMIC_RELEASE, __HIP_MEMORY_SCOPE_AGENT);
        if ((bid & 7) == 0) {
            while (__hip_atomic_load(garr, __ATOMIC_RELAXED, __HIP_MEMORY_SCOPE_AGENT) < GRPSZ)
                __builtin_amdgcn_s_sleep(1);
            __hip_atomic_fetch_add(cent, 1u, __ATOMIC_RELAXED, __HIP_MEMORY_SCOPE_AGENT);
            while (__hip_atomic_load(cent, __ATOMIC_RELAXED, __HIP_MEMORY_SCOPE_AGENT) < NGRP)
                __builtin_amdgcn_s_sleep(2);
            __hip_atomic_store(ggo, 1u, __ATOMIC_RELAXED, __HIP_MEMORY_SCOPE_AGENT);
        } else {
            while (__hip_atomic_load(ggo, __ATOMIC_RELAXED, __HIP_MEMORY_SCOPE_AGENT) == 0)
                __builtin_amdgcn_s_sleep(2);
        }
    }
    __builtin_amdgcn_sched_barrier(0);
    __syncthreads();
}

// Stage phase input into LDS. ATOMIC=true reads via agent-scope atomics.
template<int N, bool ATOMIC>
__device__ __forceinline__ void stage(const float* __restrict__ g, float* xs) {
    if constexpr (ATOMIC) {
        for (int i = threadIdx.x * 2; i < N; i += NT * 2) {
            union { unsigned long long u; float f[2]; } c;
            c.u = aload64(g + i);
            xs[i] = c.f[0]; xs[i + 1] = c.f[1];
        }
    } else {
        for (int i = threadIdx.x * 4; i < N; i += NT * 4)
            *reinterpret_cast<v4f*>(xs + i) = *reinterpret_cast<const v4f*>(g + i);
    }
    __syncthreads();
}

// CLEN multiple of 256.
template<int CLEN>
__device__ __forceinline__ void dot3(const float* __restrict__ wi,
                                     const float* __restrict__ wg,
                                     const float* __restrict__ wo,
                                     const float* __restrict__ xs,
                                     int lane, float& si, float& sg, float& so) {
    si = 0.f; sg = 0.f; so = 0.f;
    #pragma unroll 4
    for (int c0 = 0; c0 < CLEN; c0 += 256) {
        const int c = c0 + lane * 4;
        const v4f xv = *reinterpret_cast<const v4f*>(xs + c);
        const v4f av = *reinterpret_cast<const v4f*>(wi + c);
        const v4f gv = *reinterpret_cast<const v4f*>(wg + c);
        const v4f ov = *reinterpret_cast<const v4f*>(wo + c);
        si += av.x * xv.x + av.y * xv.y + av.z * xv.z + av.w * xv.w;
        sg += gv.x * xv.x + gv.y * xv.y + gv.z * xv.z + gv.w * xv.w;
        so += ov.x * xv.x + ov.y * xv.y + ov.z * xv.z + ov.w * xv.w;
    }
}

__device__ __forceinline__ void epi(float si, float sg, float so,
                                    const float* __restrict__ bi,
                                    const float* __restrict__ bh,
                                    int j, int dh, float* __restrict__ h) {
    const float gi = si + bi[j]          + bh[j];
    const float gg = sg + bi[j + 2 * dh] + bh[j + 2 * dh];
    const float go = so + bi[j + 3 * dh] + bh[j + 3 * dh];
    st_agent(h + j, sigmoidf_(go) * tanhf(sigmoidf_(gi) * tanhf(gg)));
}

// One LSTM phase over 4096 waves. SPLIT waves share a row (column split).
template<int C, int SPLIT>
__device__ __forceinline__ void cell(const float* __restrict__ w,
                                     const float* __restrict__ bi,
                                     const float* __restrict__ bh,
                                     const float* __restrict__ xs,
                                     float* __restrict__ h,
                                     int dh, int wv, int wl, int lane,
                                     float (*red)[3]) {
    constexpr int CL = C / SPLIT;
    const int j = wv / SPLIT;
    const int part = wv % SPLIT;
    const int off = part * CL;
    const float* wi = w + (size_t)j * C + off;
    const float* wg = w + ((size_t)j + 2u * (size_t)dh) * C + off;
    const float* wo = w + ((size_t)j + 3u * (size_t)dh) * C + off;
    float si, sg, so;
    dot3<CL>(wi, wg, wo, xs + off, lane, si, sg, so);
    si = wred(si); sg = wred(sg); so = wred(so);
    if constexpr (SPLIT > 1) {
        if (lane == 0) { red[wl][0] = si; red[wl][1] = sg; red[wl][2] = so; }
        __syncthreads();
        if (part == 0 && lane == 0) {
            #pragma unroll
            for (int k = 1; k < SPLIT; ++k) {
                si += red[wl + k][0]; sg += red[wl + k][1]; so += red[wl + k][2];
            }
            epi(si, sg, so, bi, bh, j, dh, h);
        }
        __syncthreads();                   // red[] reuse guard
    } else {
        if (lane == 0) epi(si, sg, so, bi, bh, j, dh, h);
    }
}

// Final linear: 4096 rows, 1 row/wave, C=2048. Plain stores to d_out.
__device__ __forceinline__ void linear1(const float* __restrict__ w,
                                        const float* __restrict__ b,
                                        const float* __restrict__ xs,
                                        float* __restrict__ y,
                                        int wv, int lane) {
    const float* wr = w + (size_t)wv * 2048;
    float s = 0.f;
    #pragma unroll 4
    for (int c0 = 0; c0 < 2048; c0 += 256) {
        const int c = c0 + lane * 4;
        const v4f xv = *reinterpret_cast<const v4f*>(xs + c);
        const v4f a  = *reinterpret_cast<const v4f*>(wr + c);
        s += a.x * xv.x + a.y * xv.y + a.z * xv.z + a.w * xv.w;
    }
    s = wred(s);
    if (lane == 0) y[wv] = s + b[wv];
}

struct Params {
    const float *x;
    const float *w0, *bi0, *bh0;  // e1l0: 2048 rows, C=4096
    const float *w1, *bi1, *bh1;  // e1l1: 2048, C=2048
    const float *w2, *bi2, *bh2;  // e2:   1024, C=2048
    const float *w3, *bi3, *bh3;  // d1l0: 1024, C=1024
    const float *w4, *bi4, *bh4;  // d1l1: 1024, C=1024
    const float *w5, *bi5, *bh5;  // d2:   2048, C=1024
    const float *ow, *ob;         // out:  4096, C=2048
    float *out;
    float *ws;
};

__global__ __launch_bounds__(NT, 4) void fused_lstm_ae(Params p) {
    __shared__ float xs[4096];
    __shared__ float red[NWAVE][3];
    const int lane = threadIdx.x & 63;
    const int wl = threadIdx.x >> 6;
    const int wv = (int)blockIdx.x * NWAVE + wl;   // 0..4095

    unsigned* bar = (unsigned*)p.ws;      // 128 KB, zeroed per call
    float* h1 = p.ws + BAR_U32;           // 2048
    float* h2 = h1 + 2048;                // 2048
    float* z  = h2 + 2048;                // 1024
    float* h3 = z  + 1024;                // 1024
    float* h4 = h3 + 1024;                // 1024
    float* h5 = h4 + 1024;                // 2048

    stage<4096, false>(p.x, xs);
    cell<4096, 2>(p.w0, p.bi0, p.bh0, xs, h1, 2048, wv, wl, lane, red);
    gbar(bar + 0 * PHASE_U32);
    stage<2048, true>(h1, xs);
    cell<2048, 2>(p.w1, p.bi1, p.bh1, xs, h2, 2048, wv, wl, lane, red);
    gbar(bar + 1 * PHASE_U32);
    stage<2048, true>(h2, xs);
    cell<2048, 4>(p.w2, p.bi2, p.bh2, xs, z, 1024, wv, wl, lane, red);
    gbar(bar + 2 * PHASE_U32);
    stage<1024, true>(z, xs);
    cell<1024, 4>(p.w3, p.bi3, p.bh3, xs, h3, 1024, wv, wl, lane, red);
    gbar(bar + 3 * PHASE_U32);
    stage<1024, true>(h3, xs);
    cell<1024, 4>(p.w4, p.bi4, p.bh4, xs, h4, 1024, wv, wl, lane, red);
    gbar(bar + 4 * PHASE_U32);
    stage<1024, true>(h4, xs);
    cell<1024, 2>(p.w5, p.bi5, p.bh5, xs, h5, 2048, wv, wl, lane, red);
    gbar(bar + 5 * PHASE_U32);
    stage<2048, true>(h5, xs);
    linear1(p.ow, p.ob, xs, p.out, wv, lane);
}

extern "C" void kernel_launch(void* const* d_in, const int* in_sizes, int n_in,
                              void* d_out, int out_size, void* d_ws, size_t ws_size,
                              hipStream_t stream)
{
    Params p;
    p.x   = (const float*)d_in[0];
    p.w0  = (const float*)d_in[1];
    p.bi0 = (const float*)d_in[3];
    p.bh0 = (const float*)d_in[4];
    p.w1  = (const float*)d_in[5];
    p.bi1 = (const float*)d_in[7];
    p.bh1 = (const float*)d_in[8];
    p.w2  = (const float*)d_in[9];
    p.bi2 = (const float*)d_in[11];
    p.bh2 = (const float*)d_in[12];
    p.w3  = (const float*)d_in[13];
    p.bi3 = (const float*)d_in[15];
    p.bh3 = (const float*)d_in[16];
    p.w4  = (const float*)d_in[17];
    p.bi4 = (const float*)d_in[19];
    p.bh4 = (const float*)d_in[20];
    p.w5  = (const float*)d_in[21];
    p.bi5 = (const float*)d_in[23];
    p.bh5 = (const float*)d_in[24];
    p.ow  = (const float*)d_in[25];
    p.ob  = (const float*)d_in[26];
    p.out = (float*)d_out;
    p.ws  = (float*)d_ws;

    // Zero barrier counters (must not persist across graph replays).
    hipMemsetAsync(d_ws, 0, BAR_U32 * sizeof(unsigned), stream);

    fused_lstm_ae<<<NB, NT, 0, stream>>>(p);
}